// Round 1
// baseline (200.943 us; speedup 1.0000x reference)
//
#include <hip/hip_runtime.h>
#include <math.h>

// Performer FAVOR+ feature map, fp32.
//   out[t][j] = ratio * (exp( (c*x[t]) . proj[j] - 0.5*||x[t]||^2 ) + eps)
//   c = 64^-0.25, ratio = 256^-0.5, eps = 1e-4
//
// Block tile: 64 tokens x 128 features (blockIdx.x = feature half, so both
// halves of a token tile dispatch adjacently for L2/L3 reuse of x).
// Thread micro-tile: 4 tokens x 8 features. VALU-bound fp32 GEMM.

#define TOKS 64
#define FH 128
#define HD 64
#define A_STRIDE 68   // pad 64->68: A-read bank aliasing 2-way (free)

__global__ __launch_bounds__(256, 3)
void performer_fm_kernel(const float* __restrict__ x,
                         const float* __restrict__ proj,
                         float* __restrict__ out) {
    // A: raw x tile [token][k], stride 68
    __shared__ __align__(16) float Al[TOKS * A_STRIDE];
    // B: (c * proj)^T, [k][swizzled j], row = 128 floats
    __shared__ __align__(16) float Bl[HD * FH];

    const int tid  = threadIdx.x;
    const int fh   = blockIdx.x;            // 0 or 1: which 128 features
    const long t0  = (long)blockIdx.y * TOKS;

    // ---- stage A: 64 tokens x 64 floats = 1024 float4, coalesced ----
    {
        const float4* xg = (const float4*)(x + t0 * HD);
        #pragma unroll
        for (int it = 0; it < 4; ++it) {
            int idx = it * 256 + tid;
            int t = idx >> 4;          // token 0..63
            int c = idx & 15;          // float4 chunk along d
            float4 v = xg[idx];
            *(float4*)&Al[t * A_STRIDE + c * 4] = v;
        }
    }
    // ---- stage B: proj[j][d] -> Bl[d][swz(j)] * normalizer (transpose) ----
    {
        const float nrm = 0.35355339059327373f;   // 64^-0.25
        const float4* pg = (const float4*)proj;
        #pragma unroll
        for (int it = 0; it < 8; ++it) {
            int idx = it * 256 + tid;             // 0..2047
            int jl  = idx >> 4;                   // local feature 0..127
            int c4  = idx & 15;                   // d-chunk 0..15
            float4 v = pg[(fh * FH + jl) * (HD / 4) + c4];
            int cc  = jl >> 2;                    // j-chunk 0..31
            int pp  = ((cc & 3) << 3) | (cc >> 2);// bank-spreading swizzle
            int pos = pp * 4 + (jl & 3);
            Bl[(c4 * 4 + 0) * FH + pos] = v.x * nrm;
            Bl[(c4 * 4 + 1) * FH + pos] = v.y * nrm;
            Bl[(c4 * 4 + 2) * FH + pos] = v.z * nrm;
            Bl[(c4 * 4 + 3) * FH + pos] = v.w * nrm;
        }
    }
    __syncthreads();

    const int nt = tid & 15;     // feature group: 8 features = chunks 2nt, 2nt+1
    const int mt = tid >> 4;     // token group: tokens 4mt..4mt+3

    const int c0 = 2 * nt, c1 = 2 * nt + 1;
    const int boff0 = (((c0 & 3) << 3) | (c0 >> 2)) * 4;
    const int boff1 = (((c1 & 3) << 3) | (c1 >> 2)) * 4;
    const int ar = mt * 4;

    float acc[4][8];
    float dsum[4];
    #pragma unroll
    for (int i = 0; i < 4; ++i) {
        dsum[i] = 0.f;
        #pragma unroll
        for (int q = 0; q < 8; ++q) acc[i][q] = 0.f;
    }

    #pragma unroll 4
    for (int k = 0; k < HD; ++k) {
        float4 b0 = *(const float4*)&Bl[k * FH + boff0];
        float4 b1 = *(const float4*)&Bl[k * FH + boff1];
        #pragma unroll
        for (int i = 0; i < 4; ++i) {
            float a = Al[(ar + i) * A_STRIDE + k];
            dsum[i]   = fmaf(a, a,    dsum[i]);
            acc[i][0] = fmaf(a, b0.x, acc[i][0]);
            acc[i][1] = fmaf(a, b0.y, acc[i][1]);
            acc[i][2] = fmaf(a, b0.z, acc[i][2]);
            acc[i][3] = fmaf(a, b0.w, acc[i][3]);
            acc[i][4] = fmaf(a, b1.x, acc[i][4]);
            acc[i][5] = fmaf(a, b1.y, acc[i][5]);
            acc[i][6] = fmaf(a, b1.z, acc[i][6]);
            acc[i][7] = fmaf(a, b1.w, acc[i][7]);
        }
    }

    const float ratio = 0.0625f;   // 256^-0.5
    const float eps   = 1e-4f;
    #pragma unroll
    for (int i = 0; i < 4; ++i) {
        const long t = t0 + ar + i;
        const float dg = 0.5f * dsum[i];
        float4 o0, o1;
        o0.x = ratio * (__expf(acc[i][0] - dg) + eps);
        o0.y = ratio * (__expf(acc[i][1] - dg) + eps);
        o0.z = ratio * (__expf(acc[i][2] - dg) + eps);
        o0.w = ratio * (__expf(acc[i][3] - dg) + eps);
        o1.x = ratio * (__expf(acc[i][4] - dg) + eps);
        o1.y = ratio * (__expf(acc[i][5] - dg) + eps);
        o1.z = ratio * (__expf(acc[i][6] - dg) + eps);
        o1.w = ratio * (__expf(acc[i][7] - dg) + eps);
        float* orow = out + t * 256 + fh * FH + nt * 8;
        *(float4*)(orow)     = o0;
        *(float4*)(orow + 4) = o1;
    }
}

extern "C" void kernel_launch(void* const* d_in, const int* in_sizes, int n_in,
                              void* d_out, int out_size, void* d_ws, size_t ws_size,
                              hipStream_t stream) {
    const float* x    = (const float*)d_in[0];
    const float* proj = (const float*)d_in[1];
    float* out        = (float*)d_out;
    const int ntok    = in_sizes[0] / HD;        // 131072
    dim3 grid(2, ntok / TOKS);                   // (feature-half, token tile)
    performer_fm_kernel<<<grid, dim3(256), 0, stream>>>(x, proj, out);
}

// Round 2
// 173.240 us; speedup vs baseline: 1.1599x; 1.1599x over previous
//
#include <hip/hip_runtime.h>
#include <math.h>

// Performer FAVOR+ feature map via bf16 hi/lo split MFMA.
//   out[t][j] = ratio * (exp( x[t] . (nrm*proj[j]) - 0.5*||x[t]||^2 ) + eps)
// x fp32 -> (hi,lo) bf16; proj likewise (pre-kernel). dot = hi*hi + hi*lo + lo*hi
// (drop lo*lo, rel err ~2^-17). MFMA f32_16x16x32_bf16; diag in exact fp32.
//
// Block: 256 thr = 4 waves; tile 64 tokens x 256 feats (x fetched once).
// Wave: 16-token rows? no -- wave w owns feats [64w,64w+64): B frags (16 x 16B)
// live in registers, loaded from frag-ordered ws (pre-kernel). A hi/lo in LDS,
// stride 72 shorts (2-way bank aliasing on ds_read_b128 = free).

typedef short bf16x8 __attribute__((ext_vector_type(8)));
typedef float f32x4  __attribute__((ext_vector_type(4)));

#define A_STR 72   // shorts; 144 B rows -> frag reads land 2-way on banks

__device__ __forceinline__ unsigned short f2bf_rne(float f) {
    unsigned u = __builtin_bit_cast(unsigned, f);
    unsigned r = u + 0x7FFFu + ((u >> 16) & 1u);
    return (unsigned short)(r >> 16);
}

__device__ __forceinline__ void f2bf_hilo(float f, unsigned short& h, unsigned short& l) {
    h = f2bf_rne(f);
    float fh = __builtin_bit_cast(float, (unsigned)h << 16);
    l = f2bf_rne(f - fh);
}

// ---- pre-kernel: proj (256x64 fp32) -> frag-ordered bf16 hi/lo in ws ----
// ws layout: [(nt*2 + kc)*2 + h][lane] of 8 bf16 (16B). g = nt*256+kc*128+h*64+lane.
__global__ void performer_prep(const float* __restrict__ proj, short* __restrict__ bfrag) {
    int g    = blockIdx.x * 256 + threadIdx.x;   // 0..4095
    int lane = g & 63;
    int h    = (g >> 6) & 1;
    int kc   = (g >> 7) & 1;
    int nt   = g >> 8;                           // 0..15
    int n    = nt * 16 + (lane & 15);
    int kb   = kc * 32 + (lane >> 4) * 8;
    const float nrm = 0.35355339059327373f;      // 64^-0.25
    float4 v0 = *(const float4*)&proj[n * 64 + kb];
    float4 v1 = *(const float4*)&proj[n * 64 + kb + 4];
    float vals[8] = {v0.x, v0.y, v0.z, v0.w, v1.x, v1.y, v1.z, v1.w};
    union { unsigned short us[8]; bf16x8 v; } o;
    #pragma unroll
    for (int j = 0; j < 8; ++j) {
        unsigned short hi, lo;
        f2bf_hilo(vals[j] * nrm, hi, lo);
        o.us[j] = h ? lo : hi;
    }
    *(bf16x8*)&bfrag[g * 8] = o.v;
}

__global__ __launch_bounds__(256, 3)
void performer_fm_kernel(const float* __restrict__ x,
                         const short* __restrict__ bfrag,
                         float* __restrict__ out) {
    __shared__ __align__(16) short Ah[64 * A_STR];
    __shared__ __align__(16) short Al[64 * A_STR];
    __shared__ float diag[64];

    const int tid  = threadIdx.x;
    const int wave = tid >> 6;
    const int lane = tid & 63;
    const int q    = lane >> 4;
    const int li   = lane & 15;
    const long t0  = (long)blockIdx.x * 64;

    // ---- B fragments: wave's 4 feature tiles x 2 K-chunks x {hi,lo} ----
    bf16x8 Bh[4][2], Bl[4][2];
    {
        const bf16x8* bw = (const bf16x8*)bfrag;
        #pragma unroll
        for (int nt = 0; nt < 4; ++nt) {
            int ntg = wave * 4 + nt;
            #pragma unroll
            for (int kc = 0; kc < 2; ++kc) {
                Bh[nt][kc] = bw[((ntg * 2 + kc) * 2 + 0) * 64 + lane];
                Bl[nt][kc] = bw[((ntg * 2 + kc) * 2 + 1) * 64 + lane];
            }
        }
    }

    // ---- stage A: 64 tokens x 64 k fp32 -> hi/lo bf16 LDS + diag ----
    {
        const float4* xg = (const float4*)(x + t0 * 64);
        #pragma unroll
        for (int it = 0; it < 4; ++it) {
            int idx = it * 256 + tid;
            int t = idx >> 4;           // token 0..63
            int c = idx & 15;           // float4 chunk along k
            float4 v = xg[idx];
            union { unsigned short us[4]; ushort4 v4; } hh, ll;
            f2bf_hilo(v.x, hh.us[0], ll.us[0]);
            f2bf_hilo(v.y, hh.us[1], ll.us[1]);
            f2bf_hilo(v.z, hh.us[2], ll.us[2]);
            f2bf_hilo(v.w, hh.us[3], ll.us[3]);
            *(ushort4*)&Ah[t * A_STR + c * 4] = hh.v4;
            *(ushort4*)&Al[t * A_STR + c * 4] = ll.v4;
            // exact fp32 ||x||^2 partial, reduce across the 16 lanes of token t
            float p = v.x * v.x + v.y * v.y + v.z * v.z + v.w * v.w;
            p += __shfl_xor(p, 1);
            p += __shfl_xor(p, 2);
            p += __shfl_xor(p, 4);
            p += __shfl_xor(p, 8);
            if ((tid & 15) == 0) diag[t] = 0.5f * p;
        }
    }
    __syncthreads();

    const float ratio = 0.0625f;   // 256^-0.5
    const float eps   = 1e-4f;
    const int wfeat   = wave * 64;

    #pragma unroll
    for (int mt = 0; mt < 4; ++mt) {
        const int arow = (mt * 16 + li) * A_STR;
        bf16x8 ah0 = *(const bf16x8*)&Ah[arow + q * 8];
        bf16x8 ah1 = *(const bf16x8*)&Ah[arow + 32 + q * 8];
        bf16x8 al0 = *(const bf16x8*)&Al[arow + q * 8];
        bf16x8 al1 = *(const bf16x8*)&Al[arow + 32 + q * 8];
        float dv[4];
        #pragma unroll
        for (int r = 0; r < 4; ++r) dv[r] = diag[mt * 16 + q * 4 + r];

        #pragma unroll
        for (int nt = 0; nt < 4; ++nt) {
            f32x4 acc = {0.f, 0.f, 0.f, 0.f};
            acc = __builtin_amdgcn_mfma_f32_16x16x32_bf16(al0, Bh[nt][0], acc, 0, 0, 0);
            acc = __builtin_amdgcn_mfma_f32_16x16x32_bf16(ah0, Bl[nt][0], acc, 0, 0, 0);
            acc = __builtin_amdgcn_mfma_f32_16x16x32_bf16(ah0, Bh[nt][0], acc, 0, 0, 0);
            acc = __builtin_amdgcn_mfma_f32_16x16x32_bf16(al1, Bh[nt][1], acc, 0, 0, 0);
            acc = __builtin_amdgcn_mfma_f32_16x16x32_bf16(ah1, Bl[nt][1], acc, 0, 0, 0);
            acc = __builtin_amdgcn_mfma_f32_16x16x32_bf16(ah1, Bh[nt][1], acc, 0, 0, 0);
            // C layout: col = lane&15 (feat), row = q*4 + reg (token-local)
            float* ob = out + (t0 + mt * 16 + q * 4) * 256 + wfeat + nt * 16 + li;
            #pragma unroll
            for (int r = 0; r < 4; ++r) {
                ob[r * 256] = ratio * (__expf(acc[r] - dv[r]) + eps);
            }
        }
    }
}

extern "C" void kernel_launch(void* const* d_in, const int* in_sizes, int n_in,
                              void* d_out, int out_size, void* d_ws, size_t ws_size,
                              hipStream_t stream) {
    const float* x    = (const float*)d_in[0];
    const float* proj = (const float*)d_in[1];
    float* out        = (float*)d_out;
    short* bfrag      = (short*)d_ws;            // 64 KB frag-ordered proj
    const int ntok    = in_sizes[0] / 64;        // 131072

    performer_prep<<<16, 256, 0, stream>>>(proj, bfrag);
    performer_fm_kernel<<<ntok / 64, 256, 0, stream>>>(x, bfrag, out);
}